// Round 13
// baseline (518.877 us; speedup 1.0000x reference)
//
#include <hip/hip_runtime.h>
#include <hip/hip_bf16.h>
#include <cstdint>

typedef float f4  __attribute__((ext_vector_type(4)));
typedef short s8v __attribute__((ext_vector_type(8)));   // 8 bf16 (4 VGPRs)
typedef int   i4v __attribute__((ext_vector_type(4)));

#define BHTD 3145728    // B*H*T*D = 2*12*2048*64
#define BTC  3145728
#define NT   2048
#define NC   768
#define NWA  1769472    // 3C*C = 2304*768
#define NWP  589824     // C*C = 768*768
#define NEG  -1e30f
// 0.125 (1/sqrt(64)) * log2(e): folded into Q at the producer so the flash
// kernel's scores are already in log2 domain (exp2 instead of expf, no scale mul)
#define QSCALE 0.18033688f
#define VP 42           // Vs row pad (21 dw, odd -> 2-way max)

static __device__ __forceinline__ short bfbits(float f) {
    return __builtin_bit_cast(short, __float2bfloat16(f));
}
static __device__ __forceinline__ float bf2f(short s) {
    return __builtin_bit_cast(float, (int)(((unsigned int)(unsigned short)s) << 16));
}
static __device__ __forceinline__ float exp2fast(float x) {
    return __builtin_amdgcn_exp2f(x);
}
// hardware packed f32->bf16 (RNE), lo -> [15:0], hi -> [31:16]
static __device__ __forceinline__ int cvtpk_bf16(float lo, float hi) {
    int r;
    asm("v_cvt_pk_bf16_f32 %0, %1, %2" : "=v"(r) : "v"(lo), "v"(hi));
    return r;
}
// async global->LDS, 16B per lane; dest = base + lane*16 (wave-uniform base)
static __device__ __forceinline__ void gl_lds16(const short* g, short* l) {
    __builtin_amdgcn_global_load_lds(
        (const __attribute__((address_space(1))) void*)g,
        (__attribute__((address_space(3))) void*)l, 16, 0, 0);
}
// row reductions across the 4 quads (lanes l16, l16+16, l16+32, l16+48)
static __device__ __forceinline__ float rowred_max(float x) {
    x = fmaxf(x, __shfl_xor(x, 16, 64));
    x = fmaxf(x, __shfl_xor(x, 32, 64));
    return x;
}
static __device__ __forceinline__ float rowred_sum(float x) {
    x += __shfl_xor(x, 16, 64);
    x += __shfl_xor(x, 32, 64);
    return x;
}

// ---------------------------------------------------------------------------
// Kernel 0: one-shot fp32->bf16 conversion. xn=x, xm=(xl+xu)/2, xr=(xu-xl)/2,
// wb=W_attn, wpb=W_proj. Removes per-block re-conversion from the GEMMs.
// ---------------------------------------------------------------------------
__global__ __launch_bounds__(256) void prep_cvt(
    const float* __restrict__ x, const float* __restrict__ xl,
    const float* __restrict__ xu, const float* __restrict__ W,
    const float* __restrict__ Wp,
    short* __restrict__ xn, short* __restrict__ xm, short* __restrict__ xr,
    short* __restrict__ wb, short* __restrict__ wpb)
{
    const size_t flat = (size_t)blockIdx.x * 256 + threadIdx.x;
    const size_t i = flat * 8;        // 1536*256*8 == BTC exactly
    {
        const f4 a0 = *(const f4*)&x[i],  a1 = *(const f4*)&x[i + 4];
        const f4 l0 = *(const f4*)&xl[i], l1 = *(const f4*)&xl[i + 4];
        const f4 u0 = *(const f4*)&xu[i], u1 = *(const f4*)&xu[i + 4];
        s8v vn, vm, vr;
#pragma unroll
        for (int j = 0; j < 4; j++) {
            vn[j]     = bfbits(a0[j]);                   vn[4 + j] = bfbits(a1[j]);
            vm[j]     = bfbits(0.5f * (l0[j] + u0[j]));  vm[4 + j] = bfbits(0.5f * (l1[j] + u1[j]));
            vr[j]     = bfbits(0.5f * (u0[j] - l0[j]));  vr[4 + j] = bfbits(0.5f * (u1[j] - l1[j]));
        }
        *(s8v*)&xn[i] = vn;
        *(s8v*)&xm[i] = vm;
        *(s8v*)&xr[i] = vr;
    }
    if (flat < NWA / 8) {
        const size_t wi = flat * 8;
        const f4 w0 = *(const f4*)&W[wi], w1 = *(const f4*)&W[wi + 4];
        s8v vw;
#pragma unroll
        for (int j = 0; j < 4; j++) { vw[j] = bfbits(w0[j]); vw[4 + j] = bfbits(w1[j]); }
        *(s8v*)&wb[wi] = vw;
    }
    if (flat < NWP / 8) {
        const size_t wi = flat * 8;
        const f4 w0 = *(const f4*)&Wp[wi], w1 = *(const f4*)&Wp[wi + 4];
        s8v vw;
#pragma unroll
        for (int j = 0; j < 4; j++) { vw[j] = bfbits(w0[j]); vw[4 + j] = bfbits(w1[j]); }
        *(s8v*)&wpb[wi] = vw;
    }
}

// ---------------------------------------------------------------------------
// Kernel 1: MFMA QKV projection, M64 x N128 tile, global_load_lds staging.
// (UNCHANGED from R12.)
// ---------------------------------------------------------------------------
__global__ __launch_bounds__(256, 3) void qkv_proj_mfma(
    const short* __restrict__ xn, const short* __restrict__ xm,
    const short* __restrict__ xr, const short* __restrict__ wb,
    short* __restrict__ qkvb)
{
    // per-buffer (shorts): Ax@0, Am@2048, Ar@4096 (each [64][32]);
    // Bw@6144 ([128][32] = 4096). Buffer = 10240 shorts = 20.5 KB.
    __shared__ short sm[2][10240];      // 40 KB
    short* Eb = &sm[0][0];              // epilogue alias [64][72] (4608 shorts)

    const int b_  = blockIdx.x;         // 0..1151
    const int xcd = b_ & 7;
    const int s_  = b_ >> 3;            // 0..143
    const int jx  = s_ % 18;
    const int ny  = xcd + 8 * (s_ / 18);   // 0..63
    const int j0 = jx * 128;            // N in [0,2304)
    const int n0 = ny * 64;             // M in [0,4096)
    const int t  = threadIdx.x;
    const int wv = t >> 6, lane = t & 63, quad = lane >> 4, l16 = lane & 15;

    const int srow = lane >> 2;
    const int cswz = (lane & 3) ^ (srow & 3);

    const size_t aoff  = (size_t)(n0 + wv * 16 + srow) * NC + cswz * 8;
    const size_t boff0 = (size_t)(j0 + wv * 16 + srow) * NC + cswz * 8;
    const size_t boff1 = (size_t)(j0 + 64 + wv * 16 + srow) * NC + cswz * 8;
    const int lws = wv * 512;           // wave's 16-row LDS window (shorts)

    f4 aN[8], aM[8], aR[8];
#pragma unroll
    for (int i = 0; i < 8; i++) { aN[i] = f4{0,0,0,0}; aM[i] = f4{0,0,0,0}; aR[i] = f4{0,0,0,0}; }

    // prologue: DMA tile 0 into buf 0
    {
        gl_lds16(&xn[aoff],  &sm[0][0    + lws]);
        gl_lds16(&xm[aoff],  &sm[0][2048 + lws]);
        gl_lds16(&xr[aoff],  &sm[0][4096 + lws]);
        gl_lds16(&wb[boff0], &sm[0][6144 + lws]);
        gl_lds16(&wb[boff1], &sm[0][8192 + lws]);
    }

    const int rsw = (quad ^ (l16 & 3)) * 8;   // swizzled read slot (shorts)

    for (int it = 0; it < NC / 32; ++it) {
        const int cb = it & 1, nb = cb ^ 1;
        __syncthreads();                       // buf[cb] DMA complete (vmcnt drain)
        if (it + 1 < NC / 32) {                // DMA next tile (flies under MFMAs)
            const size_t k1 = (size_t)(it + 1) * 32;
            gl_lds16(&xn[aoff + k1],  &sm[nb][0    + lws]);
            gl_lds16(&xm[aoff + k1],  &sm[nb][2048 + lws]);
            gl_lds16(&xr[aoff + k1],  &sm[nb][4096 + lws]);
            gl_lds16(&wb[boff0 + k1], &sm[nb][6144 + lws]);
            gl_lds16(&wb[boff1 + k1], &sm[nb][8192 + lws]);
        }
        const s8v fx = *(const s8v*)&sm[cb][       (wv * 16 + l16) * 32 + rsw];
        const s8v fm = *(const s8v*)&sm[cb][2048 + (wv * 16 + l16) * 32 + rsw];
        const s8v fr = *(const s8v*)&sm[cb][4096 + (wv * 16 + l16) * 32 + rsw];
#pragma unroll
        for (int nt = 0; nt < 8; ++nt) {
            const s8v fb = *(const s8v*)&sm[cb][6144 + (nt * 16 + l16) * 32 + rsw];
            i4v bi = __builtin_bit_cast(i4v, fb);
#pragma unroll
            for (int i = 0; i < 4; i++) bi[i] &= 0x7fff7fff;
            const s8v fa = __builtin_bit_cast(s8v, bi);
            aN[nt] = __builtin_amdgcn_mfma_f32_16x16x32_bf16(fx, fb, aN[nt], 0, 0, 0);
            aM[nt] = __builtin_amdgcn_mfma_f32_16x16x32_bf16(fm, fb, aM[nt], 0, 0, 0);
            aR[nt] = __builtin_amdgcn_mfma_f32_16x16x32_bf16(fr, fa, aR[nt], 0, 0, 0);
        }
    }

    const int p = j0 / NC, hh0 = (j0 % NC) >> 6;   // tile spans heads hh0, hh0+1
    const float osc = (p == 0) ? QSCALE : 1.0f;    // pre-scale Q for exp2-domain flash
    const int rw = t >> 2, cc16 = (t & 3) * 16;
    for (int var = 0; var < 3; ++var)
        for (int h2 = 0; h2 < 2; ++h2) {
            __syncthreads();
#pragma unroll
            for (int nt4 = 0; nt4 < 4; ++nt4) {
                const int nt = h2 * 4 + nt4;
#pragma unroll
                for (int r = 0; r < 4; ++r) {
                    const float v = (var == 0) ? aN[nt][r]
                                  : (var == 1) ? aM[nt][r] - aR[nt][r]
                                               : aM[nt][r] + aR[nt][r];
                    Eb[(wv * 16 + quad * 4 + r) * 72 + nt4 * 16 + l16] = bfbits(v * osc);
                }
            }
            __syncthreads();
            const int hh = hh0 + h2;
            short* dst = qkvb + (size_t)(var * 3 + p) * BHTD;
            if (p < 2) {       // Q,K row-major [B,H,T,D]
                const int token = n0 + rw, b = token >> 11, tt = token & 2047;
                const size_t o = ((size_t)(b * 12 + hh) * NT + tt) * 64 + cc16;
                *(s8v*)&dst[o]     = *(const s8v*)&Eb[rw * 72 + cc16];
                *(s8v*)&dst[o + 8] = *(const s8v*)&Eb[rw * 72 + cc16 + 8];
            } else {           // V transposed [B,H,D,T]
                const int d = rw;
                s8v e0, e1;
#pragma unroll
                for (int i = 0; i < 8; i++) e0[i] = Eb[(cc16 + i) * 72 + d];
#pragma unroll
                for (int i = 0; i < 8; i++) e1[i] = Eb[(cc16 + 8 + i) * 72 + d];
                const int token0 = n0 + cc16, b = token0 >> 11, tt = token0 & 2047;
                const size_t o = ((size_t)(b * 12 + hh) * 64 + d) * NT + tt;
                *(s8v*)&dst[o]     = e0;
                *(s8v*)&dst[o + 8] = e1;
            }
        }
}

// ---------------------------------------------------------------------------
// Kernel 2: MFMA flash. R13 changes: LDS bank-conflict elimination.
// (a) K stored PERMUTED: K row k -> LDS row g(k)=4(k>>3)+(k&3)+16((k>>2)&1),
//     so the sigma-permuted A-frag read becomes LINEAR rows l16+16nt
//     (g(sigma(m)+4nt) == m+16nt). At stride 35dw this is 2-way max
//     (the old sigma-read was inherently 4-way at any odd stride).
// (b) Vs pad 40->42 shorts (21 dw, odd): V reads/writes drop 4-way -> 2-way.
// Everything else unchanged from R12 (XCD-aware grid 960, balanced pairs,
// swapped QK^T with P in registers, cvt_pk pack, T13/T14, setprio).
// ---------------------------------------------------------------------------
__global__ __launch_bounds__(256) void flash_mfma(
    const short* __restrict__ qkvb, short* __restrict__ ybf,
    short* __restrict__ cand)
{
    const int b_  = blockIdx.x;            // 0..959
    const int xcd = b_ & 7;
    const int r_  = b_ >> 3;               // 0..119
    const int pr  = r_ & 7;                // 0..7
    const int r2  = r_ >> 3;               // 0..14
    const int z   = r2 % 5;
    const int bh  = xcd + 8 * (r2 / 5);    // 0..23
    const int t   = threadIdx.x;
    const int wv = t >> 6, lane = t & 63, quad = lane >> 4, l16 = lane & 15;
    const bool TWO = (z != 0);

    __shared__ short Ks[2][32 * 70];       // [buf][g(kpos)][d] pad 70 (9.0 KB)
    __shared__ short Vs[2][2][64 * VP];    // [buf][sv][d][kpos] pad 42 (21.5 KB)

    int sv, qvi, kvi, v0i, v1i;
    if (TWO) { sv = z; qvi = (sv + 1) >> 1; kvi = 2 - (sv & 1); v0i = 1; v1i = 2; }
    else     { sv = 0; qvi = 0; kvi = 0; v0i = 0; v1i = 0; }

    const size_t hb = (size_t)bh * (NT * 64);
    const short* Qp  = qkvb + (size_t)(qvi * 3 + 0) * BHTD + hb;  // [t][d] (pre-scaled)
    const short* Kp  = qkvb + (size_t)(kvi * 3 + 1) * BHTD + hb;  // [t][d]
    const short* V0p = qkvb + (size_t)(v0i * 3 + 2) * BHTD + hb;  // [d][t] !
    const short* V1p = qkvb + (size_t)(v1i * 3 + 2) * BHTD + hb;

    const int skr = t >> 3, skc = (t & 7) * 8;   // K stage: 32 x 64
    const int gkr = 4 * (skr >> 3) + (skr & 3) + 16 * ((skr >> 2) & 1);  // g(skr)
    const int svd = t >> 2, svc = (t & 3) * 8;   // V stage: 64 x 32

    for (int half = 0; half < 2; ++half) {
        const int qt = half ? (15 - pr) : pr;
        const int q0 = qt * 128;

        // Q fragments (serve as the MFMA B operand in the swapped product)
        s8v qf[2][2];
#pragma unroll
        for (int mt = 0; mt < 2; ++mt)
#pragma unroll
            for (int ch = 0; ch < 2; ++ch)
                qf[mt][ch] = *(const s8v*)&Qp[(size_t)(q0 + 32 * wv + 16 * mt + l16) * 64 + ch * 32 + quad * 8];

        float mi[2], li[2];                // per-lane: row q = rowb + l16; li = quad-partial
        mi[0] = mi[1] = NEG; li[0] = li[1] = 0.f;
        f4 acc0[2][4], acc1[2][4];
#pragma unroll
        for (int mt = 0; mt < 2; ++mt)
#pragma unroll
            for (int i = 0; i < 4; ++i) { acc0[mt][i] = f4{0,0,0,0}; acc1[mt][i] = f4{0,0,0,0}; }

        const int ktn  = 4 * qt + 4;
        const int mykt = 4 * qt + wv + 1;  // last tile this wave's rows need

        // prologue: barrier (protect prior half's live buffers), tile 0 -> buf 0
        __syncthreads();
        s8v rK, rV0, rV1;
        rK  = *(const s8v*)&Kp[(size_t)skr * 64 + skc];
        rV0 = *(const s8v*)&V0p[(size_t)svd * NT + svc];
        if (TWO) rV1 = *(const s8v*)&V1p[(size_t)svd * NT + svc];
        *(s8v*)&Ks[0][gkr * 70 + skc]    = rK;
        *(s8v*)&Vs[0][0][svd * VP + svc] = rV0;
        if (TWO) *(s8v*)&Vs[0][1][svd * VP + svc] = rV1;

        for (int kt = 0; kt < ktn; ++kt) {
            const int k0 = kt * 32;
            const int cb = kt & 1, nb = cb ^ 1;
            __syncthreads();               // buf[cb] complete for all waves
            const bool pf = (kt + 1 < ktn);
            if (pf) {                      // issue next-tile loads early
                const int k1 = k0 + 32;
                rK  = *(const s8v*)&Kp[(size_t)(k1 + skr) * 64 + skc];
                rV0 = *(const s8v*)&V0p[(size_t)svd * NT + k1 + svc];
                if (TWO) rV1 = *(const s8v*)&V1p[(size_t)svd * NT + k1 + svc];
            }
            if (kt < mykt) {
                // ---- S^T = K Q^T (log2 domain): s[mt][nt][r] =
                //      P[kpos = k0 + quad*8 + nt*4 + r][q = rowb + l16] ----
                // K A-frag row m=l16 holds K row sigma(l16)+4nt, stored at
                // LDS row g(sigma(l16)+4nt) == l16 + 16*nt (linear).
                f4 s[2][2];
#pragma unroll
                for (int mt = 0; mt < 2; ++mt) { s[mt][0] = f4{0,0,0,0}; s[mt][1] = f4{0,0,0,0}; }
                __builtin_amdgcn_s_setprio(1);
#pragma unroll
                for (int nt = 0; nt < 2; ++nt)
#pragma unroll
                    for (int ch = 0; ch < 2; ++ch) {
                        const s8v kf = *(const s8v*)&Ks[cb][(l16 + 16 * nt) * 70 + ch * 32 + quad * 8];
                        s[0][nt] = __builtin_amdgcn_mfma_f32_16x16x32_bf16(kf, qf[0][ch], s[0][nt], 0, 0, 0);
                        s[1][nt] = __builtin_amdgcn_mfma_f32_16x16x32_bf16(kf, qf[1][ch], s[1][nt], 0, 0, 0);
                    }
                __builtin_amdgcn_s_setprio(0);

                // ---- softmax + in-register P pack, per m-tile ----
                s8v pa[2];
#pragma unroll
                for (int mt = 0; mt < 2; ++mt) {
                    const int rowb = q0 + 32 * wv + 16 * mt;
                    const int qrow = rowb + l16;
                    float a[8];
#pragma unroll
                    for (int nt = 0; nt < 2; ++nt)
#pragma unroll
                        for (int r = 0; r < 4; ++r) a[nt * 4 + r] = s[mt][nt][r];
                    if (k0 + 31 > rowb) {
#pragma unroll
                        for (int nt = 0; nt < 2; ++nt)
#pragma unroll
                            for (int r = 0; r < 4; ++r)
                                if (k0 + quad * 8 + nt * 4 + r > qrow) a[nt * 4 + r] = NEG;
                    }
                    const float c = fmaxf(fmaxf(fmaxf(a[0], a[1]), fmaxf(a[2], a[3])),
                                          fmaxf(fmaxf(a[4], a[5]), fmaxf(a[6], a[7])));
                    if (__any(c - mi[mt] > 8.0f)) {     // rare: row max grew
                        const float mx = rowred_max(c); // full-row max, quad-consistent
                        const float nm = fmaxf(mi[mt], mx);
                        const float al = exp2fast(mi[mt] - nm);
                        mi[mt] = nm;
                        li[mt] *= al;
#pragma unroll
                        for (int r = 0; r < 4; ++r) {
                            // al lives at lane l16 = acc row; uniform across quads
                            const float alr = __shfl(al, (lane & 48) | (quad * 4 + r), 64);
#pragma unroll
                            for (int dt = 0; dt < 4; ++dt) acc0[mt][dt][r] *= alr;
                            if (TWO) {
#pragma unroll
                                for (int dt = 0; dt < 4; ++dt) acc1[mt][dt][r] *= alr;
                            }
                        }
                    }
                    float p[8];
#pragma unroll
                    for (int j = 0; j < 8; ++j) p[j] = exp2fast(a[j] - mi[mt]);  // <= 2^8
                    li[mt] += ((p[0] + p[1]) + (p[2] + p[3])) + ((p[4] + p[5]) + (p[6] + p[7]));
                    i4v pi;
#pragma unroll
                    for (int jj = 0; jj < 4; ++jj)
                        pi[jj] = cvtpk_bf16(p[2 * jj], p[2 * jj + 1]);
                    pa[mt] = __builtin_bit_cast(s8v, pi);
                }
                // ---- O += P V (pa is the A fragment directly) ----
                __builtin_amdgcn_s_setprio(1);
#pragma unroll
                for (int dt = 0; dt < 4; ++dt) {
                    const s8v vf0 = *(const s8v*)&Vs[cb][0][(dt * 16 + l16) * VP + quad * 8];
                    acc0[0][dt] = __builtin_amdgcn_mfma_f32_16x16x32_bf16(pa[0], vf0, acc0[0][dt], 0, 0, 0);
                    acc0[1][dt] = __builtin_amdgcn_mfma_f32_16x16x32_bf16(pa[1], vf0, acc0[1][dt], 0, 0, 0);
                    if (TWO) {
                        const s8v vf1 = *(const s8v*)&Vs[cb][1][(dt * 16 + l16) * VP + quad * 8];
                        acc1[0][dt] = __builtin_amdgcn_mfma_f32_16x16x32_bf16(pa[0], vf1, acc1[0][dt], 0, 0, 0);
                        acc1[1][dt] = __builtin_amdgcn_mfma_f32_16x16x32_bf16(pa[1], vf1, acc1[1][dt], 0, 0, 0);
                    }
                }
                __builtin_amdgcn_s_setprio(0);
            }
            if (pf) {                      // stage next tile into buf[nb]
                *(s8v*)&Ks[nb][gkr * 70 + skc]    = rK;
                *(s8v*)&Vs[nb][0][svd * VP + svc] = rV0;
                if (TWO) *(s8v*)&Vs[nb][1][svd * VP + svc] = rV1;
            }
        }

#pragma unroll
        for (int mt = 0; mt < 2; ++mt) {
            // total row sum (uniform across quads after reduce), then redistribute
            const float invq = 1.f / rowred_sum(li[mt]);
            float inv[4];
#pragma unroll
            for (int r = 0; r < 4; ++r)
                inv[r] = __shfl(invq, (lane & 48) | (quad * 4 + r), 64);
#pragma unroll
            for (int dt = 0; dt < 4; ++dt)
#pragma unroll
                for (int r = 0; r < 4; ++r) {
                    const size_t o = hb + (size_t)(q0 + 32 * wv + 16 * mt + quad * 4 + r) * 64 + dt * 16 + l16;
                    if (!TWO) {
                        ybf[o] = bfbits(acc0[mt][dt][r] * inv[r]);
                    } else {
                        const float xa = acc0[mt][dt][r] * inv[r];
                        const float xb = acc1[mt][dt][r] * inv[r];
                        cand[(size_t)(sv - 1) * BHTD + o] = bfbits(fminf(xa, xb));
                        cand[(size_t)(3 + sv) * BHTD + o] = bfbits(fmaxf(xa, xb));
                    }
                }
        }
    }
}

// ---------------------------------------------------------------------------
// Kernel 2.5: fold the 4-way candidate min/max ONCE. In-place: lo4 -> cand
// stream 0, hi4 -> cand stream 4. min/max of exact-bf16 values is exact.
// ---------------------------------------------------------------------------
__global__ __launch_bounds__(256) void prep_out(short* __restrict__ cand)
{
    const size_t i = ((size_t)blockIdx.x * 256 + threadIdx.x) * 8;
    {
        const s8v c0 = *(const s8v*)&cand[i];
        const s8v c1 = *(const s8v*)&cand[(size_t)1 * BHTD + i];
        const s8v c2 = *(const s8v*)&cand[(size_t)2 * BHTD + i];
        const s8v c3 = *(const s8v*)&cand[(size_t)3 * BHTD + i];
        s8v lo;
#pragma unroll
        for (int j = 0; j < 8; j++) {
            const float v = fminf(fminf(bf2f(c0[j]), bf2f(c1[j])),
                                  fminf(bf2f(c2[j]), bf2f(c3[j])));
            lo[j] = (short)(__builtin_bit_cast(unsigned int, v) >> 16);
        }
        *(s8v*)&cand[i] = lo;
    }
    {
        const s8v c0 = *(const s8v*)&cand[(size_t)4 * BHTD + i];
        const s8v c1 = *(const s8v*)&cand[(size_t)5 * BHTD + i];
        const s8v c2 = *(const s8v*)&cand[(size_t)6 * BHTD + i];
        const s8v c3 = *(const s8v*)&cand[(size_t)7 * BHTD + i];
        s8v hi;
#pragma unroll
        for (int j = 0; j < 8; j++) {
            const float v = fmaxf(fmaxf(bf2f(c0[j]), bf2f(c1[j])),
                                  fmaxf(bf2f(c2[j]), bf2f(c3[j])));
            hi[j] = (short)(__builtin_bit_cast(unsigned int, v) >> 16);
        }
        *(s8v*)&cand[(size_t)4 * BHTD + i] = hi;
    }
}

// ---------------------------------------------------------------------------
// Kernel 3: MFMA output projection, M64 x N128 tile, global_load_lds staging.
// (UNCHANGED from R12.)
// ---------------------------------------------------------------------------
__global__ __launch_bounds__(256) void out_proj_mfma(
    const short* __restrict__ ybf, const short* __restrict__ cand,
    const short* __restrict__ wpb, float* __restrict__ out)
{
    // per-buffer (shorts): As@0 ([64][32]=2048), Bs@2048 ([128][32]=4096)
    __shared__ short sm3[2][6144];          // 24.6 KB
    float* Eb = (float*)sm3;                // epilogue alias [64][68] floats (17.4 KB)

    const int b_  = blockIdx.x;             // 0..1151
    const int xcd = b_ & 7;
    const int s_  = b_ >> 3;                // 0..143
    const int o   = s_ % 3;
    const int jx  = (s_ / 3) % 6;
    const int ny  = xcd + 8 * (s_ / 18);    // 0..63
    const int j0 = jx * 128, n0 = ny * 64;
    const int t  = threadIdx.x;
    const int wv = t >> 6, lane = t & 63, quad = lane >> 4, l16 = lane & 15;

    const int srow = lane >> 2;
    const int cswz = (lane & 3) ^ (srow & 3);

    f4 acc[8];
#pragma unroll
    for (int i = 0; i < 8; i++) acc[i] = f4{0,0,0,0};

    // A per-lane base (head offset + in-head d added per iter)
    const int tokenS = n0 + wv * 16 + srow;
    const int bS = tokenS >> 11, ttS = tokenS & 2047;
    const size_t abase = ((size_t)(bS * 12) * NT + ttS) * 64 + cswz * 8;
    const size_t woff0 = (size_t)(j0 + wv * 16 + srow) * NC + cswz * 8;
    const size_t woff1 = (size_t)(j0 + 64 + wv * 16 + srow) * NC + cswz * 8;
    const int lws = wv * 512;
    const short* Ap = (o == 0) ? ybf : (o == 1) ? cand : cand + (size_t)4 * BHTD;

    // prologue: DMA tile 0 into buf 0
    {
        gl_lds16(&Ap[abase],   &sm3[0][0    + lws]);
        gl_lds16(&wpb[woff0],  &sm3[0][2048 + lws]);
        gl_lds16(&wpb[woff1],  &sm3[0][4096 + lws]);
    }

    const int rsw = (quad ^ (l16 & 3)) * 8;

    for (int it = 0; it < NC / 32; ++it) {
        const int cbuf = it & 1, nbuf = cbuf ^ 1;
        __syncthreads();                       // buf[cbuf] DMA complete
        if (it + 1 < NC / 32) {
            const int k1 = (it + 1) * 32;
            const int hh = k1 >> 6, d0 = k1 & 63;
            gl_lds16(&Ap[abase + (size_t)hh * (NT * 64) + d0], &sm3[nbuf][0    + lws]);
            gl_lds16(&wpb[woff0 + k1],                         &sm3[nbuf][2048 + lws]);
            gl_lds16(&wpb[woff1 + k1],                         &sm3[nbuf][4096 + lws]);
        }
        const s8v af = *(const s8v*)&sm3[cbuf][(wv * 16 + l16) * 32 + rsw];
#pragma unroll
        for (int nt = 0; nt < 8; ++nt) {
            const s8v bf = *(const s8v*)&sm3[cbuf][2048 + (nt * 16 + l16) * 32 + rsw];
            acc[nt] = __builtin_amdgcn_mfma_f32_16x16x32_bf16(af, bf, acc[nt], 0, 0, 0);
        }
    }
    const int rw = t >> 2, cc = (t & 3) * 16;
    const int token = n0 + rw;
    for (int h2 = 0; h2 < 2; ++h2) {
        __syncthreads();
#pragma unroll
        for (int nt4 = 0; nt4 < 4; ++nt4)
#pragma unroll
            for (int r = 0; r < 4; ++r)
                Eb[(wv * 16 + quad * 4 + r) * 68 + nt4 * 16 + l16] = acc[h2 * 4 + nt4][r];
        __syncthreads();
#pragma unroll
        for (int i = 0; i < 4; ++i) {
            const f4 vo = *(const f4*)&Eb[rw * 68 + cc + 4 * i];
            *(f4*)&out[(size_t)o * BTC + (size_t)token * NC + j0 + h2 * 64 + cc + 4 * i] = vo;
        }
    }
}

extern "C" void kernel_launch(void* const* d_in, const int* in_sizes, int n_in,
                              void* d_out, int out_size, void* d_ws, size_t ws_size,
                              hipStream_t stream)
{
    const float* x  = (const float*)d_in[0];
    const float* xl = (const float*)d_in[1];
    const float* xu = (const float*)d_in[2];
    const float* Wa = (const float*)d_in[3];
    const float* Wp = (const float*)d_in[4];
    float* out = (float*)d_out;

    short* qkvb = (short*)d_ws;                       // 9*BHTD bf16 = 56.6 MB
    short* ybf  = qkvb + (size_t)9 * BHTD;            // 1*BHTD bf16 =  6.3 MB
    short* cand = ybf + (size_t)BHTD;                 // 8*BHTD bf16 = 50.3 MB
    short* wpb  = cand + (size_t)8 * BHTD;            // NWP bf16   =  1.2 MB

    // prep aliases (inside cand; consumed by qkv before flash clobbers them)
    short* xn = cand;                      // BTC shorts
    short* xm = cand + (size_t)1 * BHTD;   // BTC shorts
    short* xr = cand + (size_t)2 * BHTD;   // BTC shorts
    short* wb = cand + (size_t)3 * BHTD;   // NWA shorts (fits in BHTD)

    prep_cvt     <<<dim3(1536), 256, 0, stream>>>(x, xl, xu, Wa, Wp, xn, xm, xr, wb, wpb);
    qkv_proj_mfma<<<dim3(1152), 256, 0, stream>>>(xn, xm, xr, wb, qkvb);
    flash_mfma   <<<dim3(960),  256, 0, stream>>>(qkvb, ybf, cand);
    prep_out     <<<dim3(1536), 256, 0, stream>>>(cand);
    out_proj_mfma<<<dim3(1152), 256, 0, stream>>>(ybf, cand, wpb, out);
}

// Round 14
// 371.396 us; speedup vs baseline: 1.3971x; 1.3971x over previous
//
#include <hip/hip_runtime.h>
#include <hip/hip_bf16.h>
#include <cstdint>

typedef float f4  __attribute__((ext_vector_type(4)));
typedef short s8v __attribute__((ext_vector_type(8)));   // 8 bf16 (4 VGPRs)
typedef int   i4v __attribute__((ext_vector_type(4)));

#define BHTD 3145728    // B*H*T*D = 2*12*2048*64
#define BTC  3145728
#define NT   2048
#define NC   768
#define NWA  1769472    // 3C*C = 2304*768
#define NWP  589824     // C*C = 768*768
#define NEG  -1e30f
// 0.125 (1/sqrt(64)) * log2(e): folded into Q at the producer so the flash
// kernel's scores are already in log2 domain (exp2 instead of expf, no scale mul)
#define QSCALE 0.18033688f

static __device__ __forceinline__ short bfbits(float f) {
    return __builtin_bit_cast(short, __float2bfloat16(f));
}
static __device__ __forceinline__ float bf2f(short s) {
    return __builtin_bit_cast(float, (int)(((unsigned int)(unsigned short)s) << 16));
}
static __device__ __forceinline__ float exp2fast(float x) {
    return __builtin_amdgcn_exp2f(x);
}
// hardware packed f32->bf16 (RNE), lo -> [15:0], hi -> [31:16]
static __device__ __forceinline__ int cvtpk_bf16(float lo, float hi) {
    int r;
    asm("v_cvt_pk_bf16_f32 %0, %1, %2" : "=v"(r) : "v"(lo), "v"(hi));
    return r;
}
// async global->LDS, 16B per lane; dest = base + lane*16 (wave-uniform base)
static __device__ __forceinline__ void gl_lds16(const short* g, short* l) {
    __builtin_amdgcn_global_load_lds(
        (const __attribute__((address_space(1))) void*)g,
        (__attribute__((address_space(3))) void*)l, 16, 0, 0);
}
// row reductions across the 4 quads (lanes l16, l16+16, l16+32, l16+48)
static __device__ __forceinline__ float rowred_max(float x) {
    x = fmaxf(x, __shfl_xor(x, 16, 64));
    x = fmaxf(x, __shfl_xor(x, 32, 64));
    return x;
}
static __device__ __forceinline__ float rowred_sum(float x) {
    x += __shfl_xor(x, 16, 64);
    x += __shfl_xor(x, 32, 64);
    return x;
}

// ---------------------------------------------------------------------------
// Kernel 0: one-shot fp32->bf16 conversion. xn=x, xm=(xl+xu)/2, xr=(xu-xl)/2,
// wb=W_attn, wpb=W_proj. Removes per-block re-conversion from the GEMMs.
// ---------------------------------------------------------------------------
__global__ __launch_bounds__(256) void prep_cvt(
    const float* __restrict__ x, const float* __restrict__ xl,
    const float* __restrict__ xu, const float* __restrict__ W,
    const float* __restrict__ Wp,
    short* __restrict__ xn, short* __restrict__ xm, short* __restrict__ xr,
    short* __restrict__ wb, short* __restrict__ wpb)
{
    const size_t flat = (size_t)blockIdx.x * 256 + threadIdx.x;
    const size_t i = flat * 8;        // 1536*256*8 == BTC exactly
    {
        const f4 a0 = *(const f4*)&x[i],  a1 = *(const f4*)&x[i + 4];
        const f4 l0 = *(const f4*)&xl[i], l1 = *(const f4*)&xl[i + 4];
        const f4 u0 = *(const f4*)&xu[i], u1 = *(const f4*)&xu[i + 4];
        s8v vn, vm, vr;
#pragma unroll
        for (int j = 0; j < 4; j++) {
            vn[j]     = bfbits(a0[j]);                   vn[4 + j] = bfbits(a1[j]);
            vm[j]     = bfbits(0.5f * (l0[j] + u0[j]));  vm[4 + j] = bfbits(0.5f * (l1[j] + u1[j]));
            vr[j]     = bfbits(0.5f * (u0[j] - l0[j]));  vr[4 + j] = bfbits(0.5f * (u1[j] - l1[j]));
        }
        *(s8v*)&xn[i] = vn;
        *(s8v*)&xm[i] = vm;
        *(s8v*)&xr[i] = vr;
    }
    if (flat < NWA / 8) {
        const size_t wi = flat * 8;
        const f4 w0 = *(const f4*)&W[wi], w1 = *(const f4*)&W[wi + 4];
        s8v vw;
#pragma unroll
        for (int j = 0; j < 4; j++) { vw[j] = bfbits(w0[j]); vw[4 + j] = bfbits(w1[j]); }
        *(s8v*)&wb[wi] = vw;
    }
    if (flat < NWP / 8) {
        const size_t wi = flat * 8;
        const f4 w0 = *(const f4*)&Wp[wi], w1 = *(const f4*)&Wp[wi + 4];
        s8v vw;
#pragma unroll
        for (int j = 0; j < 4; j++) { vw[j] = bfbits(w0[j]); vw[4 + j] = bfbits(w1[j]); }
        *(s8v*)&wpb[wi] = vw;
    }
}

// ---------------------------------------------------------------------------
// Kernel 1: MFMA QKV projection, M64 x N128 tile, global_load_lds staging.
// R14: swizzle key extended to (row&3)^(2*((row>>2)&1)) — rows differing by 4
// no longer share bank-starts (4-way read conflict -> free 2-way).
// ---------------------------------------------------------------------------
__global__ __launch_bounds__(256, 3) void qkv_proj_mfma(
    const short* __restrict__ xn, const short* __restrict__ xm,
    const short* __restrict__ xr, const short* __restrict__ wb,
    short* __restrict__ qkvb)
{
    // per-buffer (shorts): Ax@0, Am@2048, Ar@4096 (each [64][32]);
    // Bw@6144 ([128][32] = 4096). Buffer = 10240 shorts = 20.5 KB.
    __shared__ short sm[2][10240];      // 40 KB
    short* Eb = &sm[0][0];              // epilogue alias [64][72] (4608 shorts)

    const int b_  = blockIdx.x;         // 0..1151
    const int xcd = b_ & 7;
    const int s_  = b_ >> 3;            // 0..143
    const int jx  = s_ % 18;
    const int ny  = xcd + 8 * (s_ / 18);   // 0..63
    const int j0 = jx * 128;            // N in [0,2304)
    const int n0 = ny * 64;             // M in [0,4096)
    const int t  = threadIdx.x;
    const int wv = t >> 6, lane = t & 63, quad = lane >> 4, l16 = lane & 15;

    // staging lane geometry: lane l -> row l>>2, slot l&3,
    // source chunk (l&3)^key(row), key(row) = (row&3)^(2*((row>>2)&1))
    const int srow = lane >> 2;
    const int skey = (srow & 3) ^ (((srow >> 2) & 1) << 1);
    const int cswz = (lane & 3) ^ skey;

    const size_t aoff  = (size_t)(n0 + wv * 16 + srow) * NC + cswz * 8;
    const size_t boff0 = (size_t)(j0 + wv * 16 + srow) * NC + cswz * 8;
    const size_t boff1 = (size_t)(j0 + 64 + wv * 16 + srow) * NC + cswz * 8;
    const int lws = wv * 512;           // wave's 16-row LDS window (shorts)

    f4 aN[8], aM[8], aR[8];
#pragma unroll
    for (int i = 0; i < 8; i++) { aN[i] = f4{0,0,0,0}; aM[i] = f4{0,0,0,0}; aR[i] = f4{0,0,0,0}; }

    // prologue: DMA tile 0 into buf 0
    {
        gl_lds16(&xn[aoff],  &sm[0][0    + lws]);
        gl_lds16(&xm[aoff],  &sm[0][2048 + lws]);
        gl_lds16(&xr[aoff],  &sm[0][4096 + lws]);
        gl_lds16(&wb[boff0], &sm[0][6144 + lws]);
        gl_lds16(&wb[boff1], &sm[0][8192 + lws]);
    }

    const int rkey = (l16 & 3) ^ (((l16 >> 2) & 1) << 1);
    const int rsw  = (quad ^ rkey) * 8;       // swizzled read slot (shorts)

    for (int it = 0; it < NC / 32; ++it) {
        const int cb = it & 1, nb = cb ^ 1;
        __syncthreads();                       // buf[cb] DMA complete (vmcnt drain)
        if (it + 1 < NC / 32) {                // DMA next tile (flies under MFMAs)
            const size_t k1 = (size_t)(it + 1) * 32;
            gl_lds16(&xn[aoff + k1],  &sm[nb][0    + lws]);
            gl_lds16(&xm[aoff + k1],  &sm[nb][2048 + lws]);
            gl_lds16(&xr[aoff + k1],  &sm[nb][4096 + lws]);
            gl_lds16(&wb[boff0 + k1], &sm[nb][6144 + lws]);
            gl_lds16(&wb[boff1 + k1], &sm[nb][8192 + lws]);
        }
        const s8v fx = *(const s8v*)&sm[cb][       (wv * 16 + l16) * 32 + rsw];
        const s8v fm = *(const s8v*)&sm[cb][2048 + (wv * 16 + l16) * 32 + rsw];
        const s8v fr = *(const s8v*)&sm[cb][4096 + (wv * 16 + l16) * 32 + rsw];
#pragma unroll
        for (int nt = 0; nt < 8; ++nt) {
            const s8v fb = *(const s8v*)&sm[cb][6144 + (nt * 16 + l16) * 32 + rsw];
            i4v bi = __builtin_bit_cast(i4v, fb);
#pragma unroll
            for (int i = 0; i < 4; i++) bi[i] &= 0x7fff7fff;
            const s8v fa = __builtin_bit_cast(s8v, bi);
            aN[nt] = __builtin_amdgcn_mfma_f32_16x16x32_bf16(fx, fb, aN[nt], 0, 0, 0);
            aM[nt] = __builtin_amdgcn_mfma_f32_16x16x32_bf16(fm, fb, aM[nt], 0, 0, 0);
            aR[nt] = __builtin_amdgcn_mfma_f32_16x16x32_bf16(fr, fa, aR[nt], 0, 0, 0);
        }
    }

    const int p = j0 / NC, hh0 = (j0 % NC) >> 6;   // tile spans heads hh0, hh0+1
    const float osc = (p == 0) ? QSCALE : 1.0f;    // pre-scale Q for exp2-domain flash
    const int rw = t >> 2, cc16 = (t & 3) * 16;
    for (int var = 0; var < 3; ++var)
        for (int h2 = 0; h2 < 2; ++h2) {
            __syncthreads();
#pragma unroll
            for (int nt4 = 0; nt4 < 4; ++nt4) {
                const int nt = h2 * 4 + nt4;
#pragma unroll
                for (int r = 0; r < 4; ++r) {
                    const float v = (var == 0) ? aN[nt][r]
                                  : (var == 1) ? aM[nt][r] - aR[nt][r]
                                               : aM[nt][r] + aR[nt][r];
                    Eb[(wv * 16 + quad * 4 + r) * 72 + nt4 * 16 + l16] = bfbits(v * osc);
                }
            }
            __syncthreads();
            const int hh = hh0 + h2;
            short* dst = qkvb + (size_t)(var * 3 + p) * BHTD;
            if (p < 2) {       // Q,K row-major [B,H,T,D]
                const int token = n0 + rw, b = token >> 11, tt = token & 2047;
                const size_t o = ((size_t)(b * 12 + hh) * NT + tt) * 64 + cc16;
                *(s8v*)&dst[o]     = *(const s8v*)&Eb[rw * 72 + cc16];
                *(s8v*)&dst[o + 8] = *(const s8v*)&Eb[rw * 72 + cc16 + 8];
            } else {           // V transposed [B,H,D,T]
                const int d = rw;
                s8v e0, e1;
#pragma unroll
                for (int i = 0; i < 8; i++) e0[i] = Eb[(cc16 + i) * 72 + d];
#pragma unroll
                for (int i = 0; i < 8; i++) e1[i] = Eb[(cc16 + 8 + i) * 72 + d];
                const int token0 = n0 + cc16, b = token0 >> 11, tt = token0 & 2047;
                const size_t o = ((size_t)(b * 12 + hh) * 64 + d) * NT + tt;
                *(s8v*)&dst[o]     = e0;
                *(s8v*)&dst[o + 8] = e1;
            }
        }
}

// ---------------------------------------------------------------------------
// Kernel 2: MFMA flash, merged nominal + 4 bound branches in one launch.
// REVERTED to the R12 version exactly (202 us, 128 VGPR, 4 waves/SIMD).
// R13's K-permutation + Vs pad pushed VGPR to 132 -> 3 waves/SIMD and
// DOUBLED conflicts: reverted. Flash sits at the 128-VGPR cliff — edits
// must be VGPR-neutral.
// ---------------------------------------------------------------------------
__global__ __launch_bounds__(256) void flash_mfma(
    const short* __restrict__ qkvb, short* __restrict__ ybf,
    short* __restrict__ cand)
{
    const int b_  = blockIdx.x;            // 0..959
    const int xcd = b_ & 7;
    const int r_  = b_ >> 3;               // 0..119
    const int pr  = r_ & 7;                // 0..7
    const int r2  = r_ >> 3;               // 0..14
    const int z   = r2 % 5;
    const int bh  = xcd + 8 * (r2 / 5);    // 0..23
    const int t   = threadIdx.x;
    const int wv = t >> 6, lane = t & 63, quad = lane >> 4, l16 = lane & 15;
    const bool TWO = (z != 0);

    __shared__ short Ks[2][32 * 70];       // [buf][kpos][d] pad 70 (9.0 KB)
    __shared__ short Vs[2][2][64 * 40];    // [buf][sv][d][kpos] (20.5 KB)

    int sv, qvi, kvi, v0i, v1i;
    if (TWO) { sv = z; qvi = (sv + 1) >> 1; kvi = 2 - (sv & 1); v0i = 1; v1i = 2; }
    else     { sv = 0; qvi = 0; kvi = 0; v0i = 0; v1i = 0; }

    const size_t hb = (size_t)bh * (NT * 64);
    const short* Qp  = qkvb + (size_t)(qvi * 3 + 0) * BHTD + hb;  // [t][d] (pre-scaled)
    const short* Kp  = qkvb + (size_t)(kvi * 3 + 1) * BHTD + hb;  // [t][d]
    const short* V0p = qkvb + (size_t)(v0i * 3 + 2) * BHTD + hb;  // [d][t] !
    const short* V1p = qkvb + (size_t)(v1i * 3 + 2) * BHTD + hb;

    const int skr = t >> 3, skc = (t & 7) * 8;   // K stage: 32 x 64
    const int svd = t >> 2, svc = (t & 3) * 8;   // V stage: 64 x 32
    const int sig = (l16 >> 2) * 8 + (l16 & 3);  // K A-frag row permutation

    for (int half = 0; half < 2; ++half) {
        const int qt = half ? (15 - pr) : pr;
        const int q0 = qt * 128;

        // Q fragments (serve as the MFMA B operand in the swapped product)
        s8v qf[2][2];
#pragma unroll
        for (int mt = 0; mt < 2; ++mt)
#pragma unroll
            for (int ch = 0; ch < 2; ++ch)
                qf[mt][ch] = *(const s8v*)&Qp[(size_t)(q0 + 32 * wv + 16 * mt + l16) * 64 + ch * 32 + quad * 8];

        float mi[2], li[2];                // per-lane: row q = rowb + l16; li = quad-partial
        mi[0] = mi[1] = NEG; li[0] = li[1] = 0.f;
        f4 acc0[2][4], acc1[2][4];
#pragma unroll
        for (int mt = 0; mt < 2; ++mt)
#pragma unroll
            for (int i = 0; i < 4; ++i) { acc0[mt][i] = f4{0,0,0,0}; acc1[mt][i] = f4{0,0,0,0}; }

        const int ktn  = 4 * qt + 4;
        const int mykt = 4 * qt + wv + 1;  // last tile this wave's rows need

        // prologue: barrier (protect prior half's live buffers), tile 0 -> buf 0
        __syncthreads();
        s8v rK, rV0, rV1;
        rK  = *(const s8v*)&Kp[(size_t)skr * 64 + skc];
        rV0 = *(const s8v*)&V0p[(size_t)svd * NT + svc];
        if (TWO) rV1 = *(const s8v*)&V1p[(size_t)svd * NT + svc];
        *(s8v*)&Ks[0][skr * 70 + skc]    = rK;
        *(s8v*)&Vs[0][0][svd * 40 + svc] = rV0;
        if (TWO) *(s8v*)&Vs[0][1][svd * 40 + svc] = rV1;

        for (int kt = 0; kt < ktn; ++kt) {
            const int k0 = kt * 32;
            const int cb = kt & 1, nb = cb ^ 1;
            __syncthreads();               // buf[cb] complete for all waves
            const bool pf = (kt + 1 < ktn);
            if (pf) {                      // issue next-tile loads early
                const int k1 = k0 + 32;
                rK  = *(const s8v*)&Kp[(size_t)(k1 + skr) * 64 + skc];
                rV0 = *(const s8v*)&V0p[(size_t)svd * NT + k1 + svc];
                if (TWO) rV1 = *(const s8v*)&V1p[(size_t)svd * NT + k1 + svc];
            }
            if (kt < mykt) {
                // ---- S^T = K Q^T (log2 domain): s[mt][nt][r] =
                //      P[kpos = k0 + quad*8 + nt*4 + r][q = rowb + l16] ----
                f4 s[2][2];
#pragma unroll
                for (int mt = 0; mt < 2; ++mt) { s[mt][0] = f4{0,0,0,0}; s[mt][1] = f4{0,0,0,0}; }
                __builtin_amdgcn_s_setprio(1);
#pragma unroll
                for (int nt = 0; nt < 2; ++nt)
#pragma unroll
                    for (int ch = 0; ch < 2; ++ch) {
                        const s8v kf = *(const s8v*)&Ks[cb][(sig + nt * 4) * 70 + ch * 32 + quad * 8];
                        s[0][nt] = __builtin_amdgcn_mfma_f32_16x16x32_bf16(kf, qf[0][ch], s[0][nt], 0, 0, 0);
                        s[1][nt] = __builtin_amdgcn_mfma_f32_16x16x32_bf16(kf, qf[1][ch], s[1][nt], 0, 0, 0);
                    }
                __builtin_amdgcn_s_setprio(0);

                // ---- softmax + in-register P pack, per m-tile ----
                s8v pa[2];
#pragma unroll
                for (int mt = 0; mt < 2; ++mt) {
                    const int rowb = q0 + 32 * wv + 16 * mt;
                    const int qrow = rowb + l16;
                    float a[8];
#pragma unroll
                    for (int nt = 0; nt < 2; ++nt)
#pragma unroll
                        for (int r = 0; r < 4; ++r) a[nt * 4 + r] = s[mt][nt][r];
                    if (k0 + 31 > rowb) {
#pragma unroll
                        for (int nt = 0; nt < 2; ++nt)
#pragma unroll
                            for (int r = 0; r < 4; ++r)
                                if (k0 + quad * 8 + nt * 4 + r > qrow) a[nt * 4 + r] = NEG;
                    }
                    const float c = fmaxf(fmaxf(fmaxf(a[0], a[1]), fmaxf(a[2], a[3])),
                                          fmaxf(fmaxf(a[4], a[5]), fmaxf(a[6], a[7])));
                    if (__any(c - mi[mt] > 8.0f)) {     // rare: row max grew
                        const float mx = rowred_max(c); // full-row max, quad-consistent
                        const float nm = fmaxf(mi[mt], mx);
                        const float al = exp2fast(mi[mt] - nm);
                        mi[mt] = nm;
                        li[mt] *= al;
#pragma unroll
                        for (int r = 0; r < 4; ++r) {
                            // al lives at lane l16 = acc row; uniform across quads
                            const float alr = __shfl(al, (lane & 48) | (quad * 4 + r), 64);
#pragma unroll
                            for (int dt = 0; dt < 4; ++dt) acc0[mt][dt][r] *= alr;
                            if (TWO) {
#pragma unroll
                                for (int dt = 0; dt < 4; ++dt) acc1[mt][dt][r] *= alr;
                            }
                        }
                    }
                    float p[8];
#pragma unroll
                    for (int j = 0; j < 8; ++j) p[j] = exp2fast(a[j] - mi[mt]);  // <= 2^8
                    li[mt] += ((p[0] + p[1]) + (p[2] + p[3])) + ((p[4] + p[5]) + (p[6] + p[7]));
                    i4v pi;
#pragma unroll
                    for (int jj = 0; jj < 4; ++jj)
                        pi[jj] = cvtpk_bf16(p[2 * jj], p[2 * jj + 1]);
                    pa[mt] = __builtin_bit_cast(s8v, pi);
                }
                // ---- O += P V (pa is the A fragment directly) ----
                __builtin_amdgcn_s_setprio(1);
#pragma unroll
                for (int dt = 0; dt < 4; ++dt) {
                    const s8v vf0 = *(const s8v*)&Vs[cb][0][(dt * 16 + l16) * 40 + quad * 8];
                    acc0[0][dt] = __builtin_amdgcn_mfma_f32_16x16x32_bf16(pa[0], vf0, acc0[0][dt], 0, 0, 0);
                    acc0[1][dt] = __builtin_amdgcn_mfma_f32_16x16x32_bf16(pa[1], vf0, acc0[1][dt], 0, 0, 0);
                    if (TWO) {
                        const s8v vf1 = *(const s8v*)&Vs[cb][1][(dt * 16 + l16) * 40 + quad * 8];
                        acc1[0][dt] = __builtin_amdgcn_mfma_f32_16x16x32_bf16(pa[0], vf1, acc1[0][dt], 0, 0, 0);
                        acc1[1][dt] = __builtin_amdgcn_mfma_f32_16x16x32_bf16(pa[1], vf1, acc1[1][dt], 0, 0, 0);
                    }
                }
                __builtin_amdgcn_s_setprio(0);
            }
            if (pf) {                      // stage next tile into buf[nb]
                *(s8v*)&Ks[nb][skr * 70 + skc]    = rK;
                *(s8v*)&Vs[nb][0][svd * 40 + svc] = rV0;
                if (TWO) *(s8v*)&Vs[nb][1][svd * 40 + svc] = rV1;
            }
        }

#pragma unroll
        for (int mt = 0; mt < 2; ++mt) {
            // total row sum (uniform across quads after reduce), then redistribute
            const float invq = 1.f / rowred_sum(li[mt]);
            float inv[4];
#pragma unroll
            for (int r = 0; r < 4; ++r)
                inv[r] = __shfl(invq, (lane & 48) | (quad * 4 + r), 64);
#pragma unroll
            for (int dt = 0; dt < 4; ++dt)
#pragma unroll
                for (int r = 0; r < 4; ++r) {
                    const size_t o = hb + (size_t)(q0 + 32 * wv + 16 * mt + quad * 4 + r) * 64 + dt * 16 + l16;
                    if (!TWO) {
                        ybf[o] = bfbits(acc0[mt][dt][r] * inv[r]);
                    } else {
                        const float xa = acc0[mt][dt][r] * inv[r];
                        const float xb = acc1[mt][dt][r] * inv[r];
                        cand[(size_t)(sv - 1) * BHTD + o] = bfbits(fminf(xa, xb));
                        cand[(size_t)(3 + sv) * BHTD + o] = bfbits(fmaxf(xa, xb));
                    }
                }
        }
    }
}

// ---------------------------------------------------------------------------
// Kernel 2.5: fold the 4-way candidate min/max ONCE. In-place: lo4 -> cand
// stream 0, hi4 -> cand stream 4. min/max of exact-bf16 values is exact.
// ---------------------------------------------------------------------------
__global__ __launch_bounds__(256) void prep_out(short* __restrict__ cand)
{
    const size_t i = ((size_t)blockIdx.x * 256 + threadIdx.x) * 8;
    {
        const s8v c0 = *(const s8v*)&cand[i];
        const s8v c1 = *(const s8v*)&cand[(size_t)1 * BHTD + i];
        const s8v c2 = *(const s8v*)&cand[(size_t)2 * BHTD + i];
        const s8v c3 = *(const s8v*)&cand[(size_t)3 * BHTD + i];
        s8v lo;
#pragma unroll
        for (int j = 0; j < 8; j++) {
            const float v = fminf(fminf(bf2f(c0[j]), bf2f(c1[j])),
                                  fminf(bf2f(c2[j]), bf2f(c3[j])));
            lo[j] = (short)(__builtin_bit_cast(unsigned int, v) >> 16);
        }
        *(s8v*)&cand[i] = lo;
    }
    {
        const s8v c0 = *(const s8v*)&cand[(size_t)4 * BHTD + i];
        const s8v c1 = *(const s8v*)&cand[(size_t)5 * BHTD + i];
        const s8v c2 = *(const s8v*)&cand[(size_t)6 * BHTD + i];
        const s8v c3 = *(const s8v*)&cand[(size_t)7 * BHTD + i];
        s8v hi;
#pragma unroll
        for (int j = 0; j < 8; j++) {
            const float v = fmaxf(fmaxf(bf2f(c0[j]), bf2f(c1[j])),
                                  fmaxf(bf2f(c2[j]), bf2f(c3[j])));
            hi[j] = (short)(__builtin_bit_cast(unsigned int, v) >> 16);
        }
        *(s8v*)&cand[(size_t)4 * BHTD + i] = hi;
    }
}

// ---------------------------------------------------------------------------
// Kernel 3: MFMA output projection, M64 x N128 tile, global_load_lds staging.
// R14: same extended swizzle key as qkv (4-way read conflict -> 2-way).
// ---------------------------------------------------------------------------
__global__ __launch_bounds__(256) void out_proj_mfma(
    const short* __restrict__ ybf, const short* __restrict__ cand,
    const short* __restrict__ wpb, float* __restrict__ out)
{
    // per-buffer (shorts): As@0 ([64][32]=2048), Bs@2048 ([128][32]=4096)
    __shared__ short sm3[2][6144];          // 24.6 KB
    float* Eb = (float*)sm3;                // epilogue alias [64][68] floats (17.4 KB)

    const int b_  = blockIdx.x;             // 0..1151
    const int xcd = b_ & 7;
    const int s_  = b_ >> 3;                // 0..143
    const int o   = s_ % 3;
    const int jx  = (s_ / 3) % 6;
    const int ny  = xcd + 8 * (s_ / 18);    // 0..63
    const int j0 = jx * 128, n0 = ny * 64;
    const int t  = threadIdx.x;
    const int wv = t >> 6, lane = t & 63, quad = lane >> 4, l16 = lane & 15;

    const int srow = lane >> 2;
    const int skey = (srow & 3) ^ (((srow >> 2) & 1) << 1);
    const int cswz = (lane & 3) ^ skey;

    f4 acc[8];
#pragma unroll
    for (int i = 0; i < 8; i++) acc[i] = f4{0,0,0,0};

    // A per-lane base (head offset + in-head d added per iter)
    const int tokenS = n0 + wv * 16 + srow;
    const int bS = tokenS >> 11, ttS = tokenS & 2047;
    const size_t abase = ((size_t)(bS * 12) * NT + ttS) * 64 + cswz * 8;
    const size_t woff0 = (size_t)(j0 + wv * 16 + srow) * NC + cswz * 8;
    const size_t woff1 = (size_t)(j0 + 64 + wv * 16 + srow) * NC + cswz * 8;
    const int lws = wv * 512;
    const short* Ap = (o == 0) ? ybf : (o == 1) ? cand : cand + (size_t)4 * BHTD;

    // prologue: DMA tile 0 into buf 0
    {
        gl_lds16(&Ap[abase],   &sm3[0][0    + lws]);
        gl_lds16(&wpb[woff0],  &sm3[0][2048 + lws]);
        gl_lds16(&wpb[woff1],  &sm3[0][4096 + lws]);
    }

    const int rkey = (l16 & 3) ^ (((l16 >> 2) & 1) << 1);
    const int rsw  = (quad ^ rkey) * 8;

    for (int it = 0; it < NC / 32; ++it) {
        const int cbuf = it & 1, nbuf = cbuf ^ 1;
        __syncthreads();                       // buf[cbuf] DMA complete
        if (it + 1 < NC / 32) {
            const int k1 = (it + 1) * 32;
            const int hh = k1 >> 6, d0 = k1 & 63;
            gl_lds16(&Ap[abase + (size_t)hh * (NT * 64) + d0], &sm3[nbuf][0    + lws]);
            gl_lds16(&wpb[woff0 + k1],                         &sm3[nbuf][2048 + lws]);
            gl_lds16(&wpb[woff1 + k1],                         &sm3[nbuf][4096 + lws]);
        }
        const s8v af = *(const s8v*)&sm3[cbuf][(wv * 16 + l16) * 32 + rsw];
#pragma unroll
        for (int nt = 0; nt < 8; ++nt) {
            const s8v bf = *(const s8v*)&sm3[cbuf][2048 + (nt * 16 + l16) * 32 + rsw];
            acc[nt] = __builtin_amdgcn_mfma_f32_16x16x32_bf16(af, bf, acc[nt], 0, 0, 0);
        }
    }
    const int rw = t >> 2, cc = (t & 3) * 16;
    const int token = n0 + rw;
    for (int h2 = 0; h2 < 2; ++h2) {
        __syncthreads();
#pragma unroll
        for (int nt4 = 0; nt4 < 4; ++nt4)
#pragma unroll
            for (int r = 0; r < 4; ++r)
                Eb[(wv * 16 + quad * 4 + r) * 68 + nt4 * 16 + l16] = acc[h2 * 4 + nt4][r];
        __syncthreads();
#pragma unroll
        for (int i = 0; i < 4; ++i) {
            const f4 vo = *(const f4*)&Eb[rw * 68 + cc + 4 * i];
            *(f4*)&out[(size_t)o * BTC + (size_t)token * NC + j0 + h2 * 64 + cc + 4 * i] = vo;
        }
    }
}

extern "C" void kernel_launch(void* const* d_in, const int* in_sizes, int n_in,
                              void* d_out, int out_size, void* d_ws, size_t ws_size,
                              hipStream_t stream)
{
    const float* x  = (const float*)d_in[0];
    const float* xl = (const float*)d_in[1];
    const float* xu = (const float*)d_in[2];
    const float* Wa = (const float*)d_in[3];
    const float* Wp = (const float*)d_in[4];
    float* out = (float*)d_out;

    short* qkvb = (short*)d_ws;                       // 9*BHTD bf16 = 56.6 MB
    short* ybf  = qkvb + (size_t)9 * BHTD;            // 1*BHTD bf16 =  6.3 MB
    short* cand = ybf + (size_t)BHTD;                 // 8*BHTD bf16 = 50.3 MB
    short* wpb  = cand + (size_t)8 * BHTD;            // NWP bf16   =  1.2 MB

    // prep aliases (inside cand; consumed by qkv before flash clobbers them)
    short* xn = cand;                      // BTC shorts
    short* xm = cand + (size_t)1 * BHTD;   // BTC shorts
    short* xr = cand + (size_t)2 * BHTD;   // BTC shorts
    short* wb = cand + (size_t)3 * BHTD;   // NWA shorts (fits in BHTD)

    prep_cvt     <<<dim3(1536), 256, 0, stream>>>(x, xl, xu, Wa, Wp, xn, xm, xr, wb, wpb);
    qkv_proj_mfma<<<dim3(1152), 256, 0, stream>>>(xn, xm, xr, wb, qkvb);
    flash_mfma   <<<dim3(960),  256, 0, stream>>>(qkvb, ybf, cand);
    prep_out     <<<dim3(1536), 256, 0, stream>>>(cand);
    out_proj_mfma<<<dim3(1152), 256, 0, stream>>>(ybf, cand, wpb, out);
}